// Round 3
// baseline (479.465 us; speedup 1.0000x reference)
//
#include <hip/hip_runtime.h>

typedef short v8s __attribute__((ext_vector_type(8)));
typedef float v4f __attribute__((ext_vector_type(4)));
typedef unsigned short v4us __attribute__((ext_vector_type(4)));

__device__ __forceinline__ unsigned short f2bf(float x) {
  union { float f; unsigned int u; } c; c.f = x;
  unsigned int u = c.u;
  return (unsigned short)((u + 0x7fffu + ((u >> 16) & 1u)) >> 16);
}
__device__ __forceinline__ float bf2f(unsigned int hi16) {
  union { unsigned int u; float f; } c; c.u = hi16 << 16;
  return c.f;
}
__device__ __forceinline__ ushort2 pk(float2 v) {
  ushort2 p; p.x = f2bf(v.x); p.y = f2bf(v.y); return p;
}

// Fold BN scale/shift AND the lin_l bias:  out = relu(z*s + t'), t' = (b - rm)*s + be.
// Also zeroes the gather sentinel row N of bufA.
__global__ void bn_fold_k(const float* __restrict__ g1, const float* __restrict__ be1,
                          const float* __restrict__ rm1, const float* __restrict__ rv1,
                          const float* __restrict__ b1,
                          const float* __restrict__ g2, const float* __restrict__ be2,
                          const float* __restrict__ rm2, const float* __restrict__ rv2,
                          const float* __restrict__ b2,
                          float* __restrict__ s1, float* __restrict__ t1,
                          float* __restrict__ s2, float* __restrict__ t2,
                          unsigned short* __restrict__ bufA, int N) {
  int i = threadIdx.x;
  if (i < 128) {
    float sv = g1[i] * rsqrtf(rv1[i] + 1e-5f);
    s1[i] = sv; t1[i] = (b1[i] - rm1[i]) * sv + be1[i];
    float sw = g2[i] * rsqrtf(rv2[i] + 1e-5f);
    s2[i] = sw; t2[i] = (b2[i] - rm2[i]) * sw + be2[i];
  }
  if (i < 64) ((unsigned int*)(bufA + (long)N * 128))[i] = 0u;
}

// B pack for 256-wide GEMM: wpk[kc*8192 + n*32 + kk]; cols 0:128 = Wl, 128:256 = Wr.
template<int K, int KC>
__global__ void pack2_k(const float* __restrict__ Wl, const float* __restrict__ Wr,
                        unsigned short* __restrict__ wpk) {
  int i = blockIdx.x * 256 + threadIdx.x;
  if (i >= KC * 8192) return;
  int kk = i & 31, n = (i >> 5) & 255, kc = i >> 13;
  int k = kc * 32 + kk;
  float v = 0.f;
  if (k < K) v = (n < 128) ? Wl[k * 128 + n] : Wr[k * 128 + (n - 128)];
  wpk[i] = f2bf(v);
}

// ---------- CSR build ----------
__global__ void zero_i_k(int* __restrict__ p, int n) {
  int i = blockIdx.x * 256 + threadIdx.x;
  if (i < n) p[i] = 0;
}
__global__ void count_k(const int* __restrict__ dst, int* __restrict__ degi, int E) {
  int i = blockIdx.x * 256 + threadIdx.x;
  if (i < E) atomicAdd(&degi[dst[i]], 1);
}
__global__ __launch_bounds__(256) void scan1_k(const int* __restrict__ degi,
                                               int* __restrict__ rowptr,
                                               int* __restrict__ bsum, int N) {
  __shared__ int sd[256];
  const int t = threadIdx.x;
  const int base = blockIdx.x * 1024 + t * 4;
  int v[4];
#pragma unroll
  for (int j = 0; j < 4; ++j) v[j] = (base + j < N) ? degi[base + j] : 0;
  const int tot = v[0] + v[1] + v[2] + v[3];
  sd[t] = tot;
  __syncthreads();
  for (int off = 1; off < 256; off <<= 1) {
    int o = (t >= off) ? sd[t - off] : 0;
    __syncthreads();
    sd[t] += o;
    __syncthreads();
  }
  int e = sd[t] - tot;
#pragma unroll
  for (int j = 0; j < 4; ++j) {
    if (base + j < N) rowptr[base + j] = e;
    e += v[j];
  }
  if (t == 255) bsum[blockIdx.x] = sd[255];
}
__global__ __launch_bounds__(256) void scan2_k(int* __restrict__ bsum, int nb) {
  __shared__ int sd[256];
  const int t = threadIdx.x;
  const int v = (t < nb) ? bsum[t] : 0;
  sd[t] = v;
  __syncthreads();
  for (int off = 1; off < 256; off <<= 1) {
    int o = (t >= off) ? sd[t - off] : 0;
    __syncthreads();
    sd[t] += o;
    __syncthreads();
  }
  if (t < nb) bsum[t] = sd[t] - v;
}
__global__ void scan3_k(int* __restrict__ rowptr, int* __restrict__ cursor,
                        const int* __restrict__ bsum, int N, int E) {
  int i = blockIdx.x * 256 + threadIdx.x;
  if (i < N) {
    int v = rowptr[i] + bsum[i >> 10];
    rowptr[i] = v;
    cursor[i] = v;
  } else if (i == N) {
    rowptr[N] = E;
  }
}
__global__ void fill_k(const int* __restrict__ src, const int* __restrict__ dst,
                       int* __restrict__ cursor, int* __restrict__ nbr, int E) {
  int i = blockIdx.x * 256 + threadIdx.x;
  if (i < E) {
    int p = atomicAdd(&cursor[dst[i]], 1);
    nbr[p] = src[i];
  }
}

// ---------- dense GEMM: A(64 rows) x [Wl|Wr](256 cols) -> Ol(128) , Or(128) ----------
// SRCF32: A = x fp32 stride 130 (convert to bf16 while staging, K padded 130->160).
// else:   A = bf16 stride 128 (K = 128 exact).
// MFMA operands SWAPPED vs naive: A-operand = weight fragment (row = out-feature),
// B-operand = node fragment (col = node). D then gives each lane 4 CONSECUTIVE
// features of one node -> 8-byte coalesced stores, no LDS restaging.
// In-place allowed: Or may alias Asrc (bf16 path) — staging reads drain before the
// barrier, stores happen after; each block touches only its own 64 rows.
template<int KC, bool SRCF32>
__global__ __launch_bounds__(256) void gemm2_k(const void* __restrict__ Asrc,
                                               const unsigned short* __restrict__ wpk,
                                               unsigned short* __restrict__ Ol,
                                               unsigned short* __restrict__ Or, int N) {
  constexpr int KP = KC * 32;
  constexpr int LDA = KP + 8;
  __shared__ __align__(16) unsigned short a_s[64][LDA];
  const int tid = threadIdx.x;
  const int node0 = blockIdx.x * 64;
  const int row = tid >> 2, t4 = tid & 3;
  const int node = node0 + row;

  if constexpr (SRCF32) {
    const float* xr = (const float*)Asrc + (long)node * 130;
#pragma unroll
    for (int j = 0; j < 16; ++j) {   // floats [8j+2t4, 8j+2t4+2) -> covers [0,128)
      float2 v = make_float2(0.f, 0.f);
      if (node < N) v = *(const float2*)(xr + 8 * j + 2 * t4);
      *(ushort2*)&a_s[row][8 * j + 2 * t4] = pk(v);
    }
    v8s z = {0, 0, 0, 0, 0, 0, 0, 0};
    if (t4 == 0 && node < N) {       // elems 128,129 + zero pad to 160
      float2 v = *(const float2*)(xr + 128);
      z[0] = (short)f2bf(v.x); z[1] = (short)f2bf(v.y);
    }
    *(v8s*)&a_s[row][128 + t4 * 8] = z;
  } else {
    const unsigned short* hr = (const unsigned short*)Asrc + (long)node * 128;
#pragma unroll
    for (int i = 0; i < KC; ++i) {
      const int c = t4 + 4 * i;
      v8s v = {0, 0, 0, 0, 0, 0, 0, 0};
      if (node < N) v = *(const v8s*)(hr + 8 * c);
      *(v8s*)&a_s[row][c * 8] = v;
    }
  }
  __syncthreads();

  const int wave = tid >> 6, lane = tid & 63;
  const int quad = lane >> 4, l16 = lane & 15;
  v4f acc[4][4];
#pragma unroll
  for (int mt = 0; mt < 4; ++mt)
#pragma unroll
    for (int nt = 0; nt < 4; ++nt) acc[mt][nt] = (v4f){0.f, 0.f, 0.f, 0.f};

  // weight fragment (A-operand): row = l16 -> feature (wave*64 + nt*16 + l16),
  // k = quad*8 + j. Address pattern identical to the old B-load.
  const unsigned short* wb = wpk + (wave * 64 + l16) * 32 + quad * 8;
#pragma unroll
  for (int kc = 0; kc < KC; ++kc) {
    v8s wf[4];
#pragma unroll
    for (int nt = 0; nt < 4; ++nt)
      wf[nt] = *(const v8s*)(wb + kc * 8192 + nt * 512);
#pragma unroll
    for (int mt = 0; mt < 4; ++mt) {
      // node fragment (B-operand): col = l16 -> node (mt*16 + l16), k = quad*8 + j.
      v8s nf = *(const v8s*)(&a_s[mt * 16 + l16][kc * 32 + quad * 8]);
#pragma unroll
      for (int nt = 0; nt < 4; ++nt)
        acc[mt][nt] = __builtin_amdgcn_mfma_f32_16x16x32_bf16(wf[nt], nf, acc[mt][nt], 0, 0, 0);
    }
  }

  // D layout: col = l16 -> node mt*16+l16, row = quad*4+r -> feature offset.
  // Each lane: 4 consecutive bf16 feats of one node -> one 8 B store.
  unsigned short* ob = (wave < 2) ? Ol : Or;
  const int cb = (wave & 1) * 64;
#pragma unroll
  for (int mt = 0; mt < 4; ++mt) {
    const int rw = node0 + mt * 16 + l16;
    if (rw < N) {
#pragma unroll
      for (int nt = 0; nt < 4; ++nt) {
        const int oc = cb + nt * 16 + quad * 4;
        v4us v;
        v[0] = f2bf(acc[mt][nt][0]);
        v[1] = f2bf(acc[mt][nt][1]);
        v[2] = f2bf(acc[mt][nt][2]);
        v[3] = f2bf(acc[mt][nt][3]);
        *(v4us*)(ob + (long)rw * 128 + oc) = v;
      }
    }
  }
}

// ---------- fused aggregate: out = relu((mean(gsrc[nbr]) + rsrc[node]) * s + t) ----------
// 4 nodes/wave, 16 nodes/block. 256-B rows: lane reads one u32 (2 bf16) per neighbor row.
// In-place allowed: out may alias rsrc (root read data-depends before the write).
template<bool OUTF32>
__global__ __launch_bounds__(256) void spmm_f_k(const unsigned short* __restrict__ gsrc,
                                                const unsigned short* __restrict__ rsrc,
                                                const int* __restrict__ rowptr,
                                                const int* __restrict__ nbr,
                                                const float* __restrict__ sc,
                                                const float* __restrict__ tc,
                                                void* __restrict__ out, int N) {
  const int w = threadIdx.x >> 6, lane = threadIdx.x & 63;
  const int nb = blockIdx.x * 16 + w * 4;
  if (nb >= N) return;

  int rp = 0;
  if (lane <= 4 && nb + lane <= N) rp = rowptr[nb + lane];
  int d[4], r0[4], myn[4];
  float2 a[4];
#pragma unroll
  for (int r = 0; r < 4; ++r) {
    r0[r] = __shfl(rp, r, 64);
    const int r1 = __shfl(rp, r + 1, 64);
    d[r] = (nb + r < N) ? (r1 - r0[r]) : 0;
    a[r] = make_float2(0.f, 0.f);
    myn[r] = N;
    if (lane < min(d[r], 64)) myn[r] = nbr[r0[r] + lane];
  }
  const int dm = max(max(d[0], d[1]), max(d[2], d[3]));

  if (dm <= 64) {
    for (int e0 = 0; e0 < dm; e0 += 8) {
      unsigned int u[4][8];
#pragma unroll
      for (int j = 0; j < 8; ++j)
#pragma unroll
        for (int r = 0; r < 4; ++r) {
          const int e = e0 + j;
          const int idx = (e < d[r]) ? __shfl(myn[r], e, 64) : N;
          u[r][j] = *(const unsigned int*)(gsrc + (long)idx * 128 + 2 * lane);
        }
#pragma unroll
      for (int r = 0; r < 4; ++r)
#pragma unroll
        for (int j = 0; j < 8; ++j) {
          a[r].x += bf2f(u[r][j] & 0xffffu);
          a[r].y += bf2f(u[r][j] >> 16);
        }
    }
  } else {  // rare huge-degree fallback
    for (int r = 0; r < 4; ++r) {
      for (int base = r0[r]; base < r0[r] + d[r]; base += 64) {
        const int cnt = min(64, r0[r] + d[r] - base);
        const int mn = (lane < cnt) ? nbr[base + lane] : N;
        for (int e = 0; e < cnt; ++e) {
          const unsigned int uu =
              *(const unsigned int*)(gsrc + (long)__shfl(mn, e, 64) * 128 + 2 * lane);
          a[r].x += bf2f(uu & 0xffffu);
          a[r].y += bf2f(uu >> 16);
        }
      }
    }
  }

  const float2 sv = *(const float2*)(sc + 2 * lane);
  const float2 tv = *(const float2*)(tc + 2 * lane);
#pragma unroll
  for (int r = 0; r < 4; ++r) {
    if (nb + r < N) {
      const float inv = 1.0f / fmaxf((float)d[r], 1.0f);
      const unsigned int ur = *(const unsigned int*)(rsrc + (long)(nb + r) * 128 + 2 * lane);
      float yx = a[r].x * inv + bf2f(ur & 0xffffu);
      float yy = a[r].y * inv + bf2f(ur >> 16);
      yx = fmaxf(yx * sv.x + tv.x, 0.f);
      yy = fmaxf(yy * sv.y + tv.y, 0.f);
      if (OUTF32) {
        *(float2*)((float*)out + (long)(nb + r) * 128 + 2 * lane) = make_float2(yx, yy);
      } else {
        *(ushort2*)((unsigned short*)out + (long)(nb + r) * 128 + 2 * lane) =
            pk(make_float2(yx, yy));
      }
    }
  }
}

extern "C" void kernel_launch(void* const* d_in, const int* in_sizes, int n_in,
                              void* d_out, int out_size, void* d_ws, size_t ws_size,
                              hipStream_t stream) {
  const float* x   = (const float*)d_in[0];
  const int*   ei  = (const int*)d_in[1];
  const float* W1l = (const float*)d_in[2];
  const float* b1  = (const float*)d_in[3];
  const float* W1r = (const float*)d_in[4];
  const float* g1  = (const float*)d_in[5];
  const float* be1 = (const float*)d_in[6];
  const float* rm1 = (const float*)d_in[7];
  const float* rv1 = (const float*)d_in[8];
  const float* W2l = (const float*)d_in[9];
  const float* b2  = (const float*)d_in[10];
  const float* W2r = (const float*)d_in[11];
  const float* g2  = (const float*)d_in[12];
  const float* be2 = (const float*)d_in[13];
  const float* rm2 = (const float*)d_in[14];
  const float* rv2 = (const float*)d_in[15];

  const int E = in_sizes[1] / 2;
  const int N = in_sizes[0] / 130;
  const int* src = ei;
  const int* dst = ei + E;

  // workspace carve: two (N+1)x128 bf16 ping-pong buffers + packs + CSR (~106 MB)
  unsigned short* bufA = (unsigned short*)d_ws;            // P1l -> P2l (gather targets)
  unsigned short* bufB = bufA + (size_t)(N + 1) * 128;     // P1r -> h1 -> P2r (root/in-place)
  unsigned short* wpka = bufB + (size_t)(N + 1) * 128;     // 5*8192
  unsigned short* wpkb = wpka + 5 * 8192;                  // 4*8192
  float* s1 = (float*)(wpkb + 4 * 8192);
  float* t1 = s1 + 128;
  float* s2 = t1 + 128;
  float* t2 = s2 + 128;
  int* degi   = (int*)(t2 + 128);   // N (reused as cursor)
  int* rowptr = degi + N;           // N+1
  int* bsum   = rowptr + N + 1;     // 256
  int* nbr    = bsum + 256;         // E

  hipLaunchKernelGGL(bn_fold_k, dim3(1), dim3(128), 0, stream,
                     g1, be1, rm1, rv1, b1, g2, be2, rm2, rv2, b2,
                     s1, t1, s2, t2, bufA, N);
  hipLaunchKernelGGL((pack2_k<130, 5>), dim3(160), dim3(256), 0, stream, W1l, W1r, wpka);
  hipLaunchKernelGGL((pack2_k<128, 4>), dim3(128), dim3(256), 0, stream, W2l, W2r, wpkb);

  // CSR build
  hipLaunchKernelGGL(zero_i_k, dim3((N + 255) / 256), dim3(256), 0, stream, degi, N);
  hipLaunchKernelGGL(count_k, dim3((E + 255) / 256), dim3(256), 0, stream, dst, degi, E);
  const int nb = (N + 1023) / 1024;
  hipLaunchKernelGGL(scan1_k, dim3(nb), dim3(256), 0, stream, degi, rowptr, bsum, N);
  hipLaunchKernelGGL(scan2_k, dim3(1), dim3(256), 0, stream, bsum, nb);
  hipLaunchKernelGGL(scan3_k, dim3((N + 256) / 256), dim3(256), 0, stream,
                     rowptr, degi, bsum, N, E);
  hipLaunchKernelGGL(fill_k, dim3((E + 255) / 256), dim3(256), 0, stream,
                     src, dst, degi, nbr, E);

  const int ngb = (N + 63) / 64;
  const int nsb = (N + 15) / 16;

  // layer 1: P1l|P1r = x @ [W1l|W1r]; h1 = relu((mean(P1l[nbr]) + P1r)*s1 + t1') over P1r
  hipLaunchKernelGGL((gemm2_k<5, true>), dim3(ngb), dim3(256), 0, stream,
                     (const void*)x, wpka, bufA, bufB, N);
  hipLaunchKernelGGL((spmm_f_k<false>), dim3(nsb), dim3(256), 0, stream,
                     bufA, bufB, rowptr, nbr, s1, t1, (void*)bufB, N);
  // layer 2: P2l|P2r = h1 @ [W2l|W2r] (in-place over bufA/bufB); out fp32
  hipLaunchKernelGGL((gemm2_k<4, false>), dim3(ngb), dim3(256), 0, stream,
                     (const void*)bufB, wpkb, bufA, bufB, N);
  hipLaunchKernelGGL((spmm_f_k<true>), dim3(nsb), dim3(256), 0, stream,
                     bufA, bufB, rowptr, nbr, s2, t2, d_out, N);
}

// Round 4
// 447.180 us; speedup vs baseline: 1.0722x; 1.0722x over previous
//
#include <hip/hip_runtime.h>

typedef short v8s __attribute__((ext_vector_type(8)));
typedef float v4f __attribute__((ext_vector_type(4)));
typedef unsigned short v4us __attribute__((ext_vector_type(4)));

__device__ __forceinline__ unsigned short f2bf(float x) {
  union { float f; unsigned int u; } c; c.f = x;
  unsigned int u = c.u;
  return (unsigned short)((u + 0x7fffu + ((u >> 16) & 1u)) >> 16);
}
__device__ __forceinline__ float bf2f(unsigned int hi16) {
  union { unsigned int u; float f; } c; c.u = hi16 << 16;
  return c.f;
}
__device__ __forceinline__ ushort2 pk(float2 v) {
  ushort2 p; p.x = f2bf(v.x); p.y = f2bf(v.y); return p;
}

// Fold BN scale/shift AND the lin_l bias:  out = relu(z*s + t'), t' = (b - rm)*s + be.
// Also zeroes the gather sentinel row N of bufA.
__global__ void bn_fold_k(const float* __restrict__ g1, const float* __restrict__ be1,
                          const float* __restrict__ rm1, const float* __restrict__ rv1,
                          const float* __restrict__ b1,
                          const float* __restrict__ g2, const float* __restrict__ be2,
                          const float* __restrict__ rm2, const float* __restrict__ rv2,
                          const float* __restrict__ b2,
                          float* __restrict__ s1, float* __restrict__ t1,
                          float* __restrict__ s2, float* __restrict__ t2,
                          unsigned short* __restrict__ bufA, int N) {
  int i = threadIdx.x;
  if (i < 128) {
    float sv = g1[i] * rsqrtf(rv1[i] + 1e-5f);
    s1[i] = sv; t1[i] = (b1[i] - rm1[i]) * sv + be1[i];
    float sw = g2[i] * rsqrtf(rv2[i] + 1e-5f);
    s2[i] = sw; t2[i] = (b2[i] - rm2[i]) * sw + be2[i];
  }
  if (i < 64) ((unsigned int*)(bufA + (long)N * 128))[i] = 0u;
}

// B pack for 256-wide GEMM: wpk[kc*8192 + n*32 + kk]; cols 0:128 = Wl, 128:256 = Wr.
template<int K, int KC>
__global__ void pack2_k(const float* __restrict__ Wl, const float* __restrict__ Wr,
                        unsigned short* __restrict__ wpk) {
  int i = blockIdx.x * 256 + threadIdx.x;
  if (i >= KC * 8192) return;
  int kk = i & 31, n = (i >> 5) & 255, kc = i >> 13;
  int k = kc * 32 + kk;
  float v = 0.f;
  if (k < K) v = (n < 128) ? Wl[k * 128 + n] : Wr[k * 128 + (n - 128)];
  wpk[i] = f2bf(v);
}

// ---------- CSR build ----------
__global__ void zero_i_k(int* __restrict__ p, int n) {
  int i = blockIdx.x * 256 + threadIdx.x;
  if (i < n) p[i] = 0;
}
__global__ void count_k(const int* __restrict__ dst, int* __restrict__ degi, int E) {
  int i = blockIdx.x * 256 + threadIdx.x;
  if (i < E) atomicAdd(&degi[dst[i]], 1);
}
__global__ __launch_bounds__(256) void scan1_k(const int* __restrict__ degi,
                                               int* __restrict__ rowptr,
                                               int* __restrict__ bsum, int N) {
  __shared__ int sd[256];
  const int t = threadIdx.x;
  const int base = blockIdx.x * 1024 + t * 4;
  int v[4];
#pragma unroll
  for (int j = 0; j < 4; ++j) v[j] = (base + j < N) ? degi[base + j] : 0;
  const int tot = v[0] + v[1] + v[2] + v[3];
  sd[t] = tot;
  __syncthreads();
  for (int off = 1; off < 256; off <<= 1) {
    int o = (t >= off) ? sd[t - off] : 0;
    __syncthreads();
    sd[t] += o;
    __syncthreads();
  }
  int e = sd[t] - tot;
#pragma unroll
  for (int j = 0; j < 4; ++j) {
    if (base + j < N) rowptr[base + j] = e;
    e += v[j];
  }
  if (t == 255) bsum[blockIdx.x] = sd[255];
}
__global__ __launch_bounds__(256) void scan2_k(int* __restrict__ bsum, int nb) {
  __shared__ int sd[256];
  const int t = threadIdx.x;
  const int v = (t < nb) ? bsum[t] : 0;
  sd[t] = v;
  __syncthreads();
  for (int off = 1; off < 256; off <<= 1) {
    int o = (t >= off) ? sd[t - off] : 0;
    __syncthreads();
    sd[t] += o;
    __syncthreads();
  }
  if (t < nb) bsum[t] = sd[t] - v;
}
__global__ void scan3_k(int* __restrict__ rowptr, int* __restrict__ cursor,
                        const int* __restrict__ bsum, int N, int E) {
  int i = blockIdx.x * 256 + threadIdx.x;
  if (i < N) {
    int v = rowptr[i] + bsum[i >> 10];
    rowptr[i] = v;
    cursor[i] = v;
  } else if (i == N) {
    rowptr[N] = E;
  }
}
__global__ void fill_k(const int* __restrict__ src, const int* __restrict__ dst,
                       int* __restrict__ cursor, int* __restrict__ nbr, int E) {
  int i = blockIdx.x * 256 + threadIdx.x;
  if (i < E) {
    int p = atomicAdd(&cursor[dst[i]], 1);
    nbr[p] = src[i];
  }
}

// ---------- dense GEMM: A(64 rows) x [Wl|Wr](256 cols) -> Ol(128) , Or(128) ----------
// SRCF32: A = x fp32 stride 130. Staging is LINEAR-COALESCED: the 64-row tile is
//   33280 contiguous bytes (16B-aligned since 64*520%16==0). Each thread issues 9
//   independent float4 loads (1-segment wave transactions), converts to bf16, and
//   scatter-writes pairs to LDS via exact magic-div row=(p*4033)>>18 (p<4160).
// else: A = bf16 stride 128; linear v8s loads, row = u>>4.
// MFMA operands swapped (A=weights, B=nodes) -> D gives 4 consecutive feats/lane.
// In-place allowed: Or may alias Asrc (bf16 path) — each block reads/writes only
// its own 64 rows; staging reads drain before the barrier, stores after.
template<int KC, bool SRCF32>
__global__ __launch_bounds__(256) void gemm2_k(const void* __restrict__ Asrc,
                                               const unsigned short* __restrict__ wpk,
                                               unsigned short* __restrict__ Ol,
                                               unsigned short* __restrict__ Or, int N) {
  constexpr int KP = KC * 32;
  constexpr int LDA = KP + 8;
  __shared__ __align__(16) unsigned short a_s[64][LDA];
  const int tid = threadIdx.x;
  const int node0 = blockIdx.x * 64;

  if constexpr (SRCF32) {
    // zero cols [130,136) and [136,168): disjoint from data cols [0,130)
    {
      const int zr = tid >> 2, zq = tid & 3;
      v8s z = {0, 0, 0, 0, 0, 0, 0, 0};
      *(v8s*)&a_s[zr][136 + zq * 8] = z;
      if (tid < 192) {
        const int r3 = tid / 3, p3 = tid - 3 * r3;
        *(unsigned int*)&a_s[r3][130 + 2 * p3] = 0u;
      }
    }
    const float* xb = (const float*)Asrc + (long)node0 * 130;
    if (node0 + 64 <= N) {      // full tile: unguarded linear float4 sweep
      float4 v[9];
#pragma unroll
      for (int i = 0; i < 9; ++i) {
        const int g = i * 256 + tid;
        if (g < 2080) v[i] = *(const float4*)(xb + 4 * g);
      }
#pragma unroll
      for (int i = 0; i < 9; ++i) {
        const int g = i * 256 + tid;
        if (g < 2080) {
          const int p0 = 2 * g, p1 = 2 * g + 1;
          const int r0_ = (p0 * 4033) >> 18, r1_ = (p1 * 4033) >> 18;
          const int c0_ = p0 - 65 * r0_, c1_ = p1 - 65 * r1_;
          *(ushort2*)&a_s[r0_][2 * c0_] = pk(make_float2(v[i].x, v[i].y));
          *(ushort2*)&a_s[r1_][2 * c1_] = pk(make_float2(v[i].z, v[i].w));
        }
      }
    } else {                    // partial tail tile: per-pair guarded float2
      for (int i = 0; i < 9; ++i) {
        const int g = i * 256 + tid;
        if (g < 2080) {
#pragma unroll
          for (int h = 0; h < 2; ++h) {
            const int p = 2 * g + h;
            const int r = (p * 4033) >> 18;
            const int c = p - 65 * r;
            float2 vv = make_float2(0.f, 0.f);
            if (node0 + r < N)
              vv = *(const float2*)((const float*)Asrc + (long)(node0 + r) * 130 + 2 * c);
            *(ushort2*)&a_s[r][2 * c] = pk(vv);
          }
        }
      }
    }
  } else {
    // bf16 source, stride 128 shorts: 64*16 = 1024 v8s units, KC(=4)*256 = 1024
    const unsigned short* hb = (const unsigned short*)Asrc + (long)node0 * 128;
    v8s v[KC];
#pragma unroll
    for (int i = 0; i < KC; ++i) {
      const int u = i * 256 + tid;
      const int r = u >> 4;
      v[i] = (v8s){0, 0, 0, 0, 0, 0, 0, 0};
      if (node0 + r < N) v[i] = *(const v8s*)(hb + 8 * u);
    }
#pragma unroll
    for (int i = 0; i < KC; ++i) {
      const int u = i * 256 + tid;
      *(v8s*)&a_s[u >> 4][(u & 15) * 8] = v[i];
    }
  }
  __syncthreads();

  const int wave = tid >> 6, lane = tid & 63;
  const int quad = lane >> 4, l16 = lane & 15;
  v4f acc[4][4];
#pragma unroll
  for (int mt = 0; mt < 4; ++mt)
#pragma unroll
    for (int nt = 0; nt < 4; ++nt) acc[mt][nt] = (v4f){0.f, 0.f, 0.f, 0.f};

  // weight fragment (A-operand): row = l16 -> feature (wave*64 + nt*16 + l16)
  const unsigned short* wb = wpk + (wave * 64 + l16) * 32 + quad * 8;
#pragma unroll
  for (int kc = 0; kc < KC; ++kc) {
    v8s wf[4];
#pragma unroll
    for (int nt = 0; nt < 4; ++nt)
      wf[nt] = *(const v8s*)(wb + kc * 8192 + nt * 512);
#pragma unroll
    for (int mt = 0; mt < 4; ++mt) {
      // node fragment (B-operand): col = l16 -> node (mt*16 + l16)
      v8s nf = *(const v8s*)(&a_s[mt * 16 + l16][kc * 32 + quad * 8]);
#pragma unroll
      for (int nt = 0; nt < 4; ++nt)
        acc[mt][nt] = __builtin_amdgcn_mfma_f32_16x16x32_bf16(wf[nt], nf, acc[mt][nt], 0, 0, 0);
    }
  }

  // D layout: col = l16 -> node mt*16+l16, row = quad*4+r -> feature offset.
  unsigned short* ob = (wave < 2) ? Ol : Or;
  const int cb = (wave & 1) * 64;
#pragma unroll
  for (int mt = 0; mt < 4; ++mt) {
    const int rw = node0 + mt * 16 + l16;
    if (rw < N) {
#pragma unroll
      for (int nt = 0; nt < 4; ++nt) {
        const int oc = cb + nt * 16 + quad * 4;
        v4us v;
        v[0] = f2bf(acc[mt][nt][0]);
        v[1] = f2bf(acc[mt][nt][1]);
        v[2] = f2bf(acc[mt][nt][2]);
        v[3] = f2bf(acc[mt][nt][3]);
        *(v4us*)(ob + (long)rw * 128 + oc) = v;
      }
    }
  }
}

// ---------- fused aggregate: out = relu((mean(gsrc[nbr]) + rsrc[node]) * s + t) ----------
// 4 nodes/wave, 16 nodes/block. 256-B rows: lane reads one u32 (2 bf16) per neighbor row.
// In-place allowed: out may alias rsrc (root read data-depends before the write).
template<bool OUTF32>
__global__ __launch_bounds__(256) void spmm_f_k(const unsigned short* __restrict__ gsrc,
                                                const unsigned short* __restrict__ rsrc,
                                                const int* __restrict__ rowptr,
                                                const int* __restrict__ nbr,
                                                const float* __restrict__ sc,
                                                const float* __restrict__ tc,
                                                void* __restrict__ out, int N) {
  const int w = threadIdx.x >> 6, lane = threadIdx.x & 63;
  const int nb = blockIdx.x * 16 + w * 4;
  if (nb >= N) return;

  int rp = 0;
  if (lane <= 4 && nb + lane <= N) rp = rowptr[nb + lane];
  int d[4], r0[4], myn[4];
  float2 a[4];
#pragma unroll
  for (int r = 0; r < 4; ++r) {
    r0[r] = __shfl(rp, r, 64);
    const int r1 = __shfl(rp, r + 1, 64);
    d[r] = (nb + r < N) ? (r1 - r0[r]) : 0;
    a[r] = make_float2(0.f, 0.f);
    myn[r] = N;
    if (lane < min(d[r], 64)) myn[r] = nbr[r0[r] + lane];
  }
  const int dm = max(max(d[0], d[1]), max(d[2], d[3]));

  if (dm <= 64) {
    for (int e0 = 0; e0 < dm; e0 += 8) {
      unsigned int u[4][8];
#pragma unroll
      for (int j = 0; j < 8; ++j)
#pragma unroll
        for (int r = 0; r < 4; ++r) {
          const int e = e0 + j;
          const int idx = (e < d[r]) ? __shfl(myn[r], e, 64) : N;
          u[r][j] = *(const unsigned int*)(gsrc + (long)idx * 128 + 2 * lane);
        }
#pragma unroll
      for (int r = 0; r < 4; ++r)
#pragma unroll
        for (int j = 0; j < 8; ++j) {
          a[r].x += bf2f(u[r][j] & 0xffffu);
          a[r].y += bf2f(u[r][j] >> 16);
        }
    }
  } else {  // rare huge-degree fallback
    for (int r = 0; r < 4; ++r) {
      for (int base = r0[r]; base < r0[r] + d[r]; base += 64) {
        const int cnt = min(64, r0[r] + d[r] - base);
        const int mn = (lane < cnt) ? nbr[base + lane] : N;
        for (int e = 0; e < cnt; ++e) {
          const unsigned int uu =
              *(const unsigned int*)(gsrc + (long)__shfl(mn, e, 64) * 128 + 2 * lane);
          a[r].x += bf2f(uu & 0xffffu);
          a[r].y += bf2f(uu >> 16);
        }
      }
    }
  }

  const float2 sv = *(const float2*)(sc + 2 * lane);
  const float2 tv = *(const float2*)(tc + 2 * lane);
#pragma unroll
  for (int r = 0; r < 4; ++r) {
    if (nb + r < N) {
      const float inv = 1.0f / fmaxf((float)d[r], 1.0f);
      const unsigned int ur = *(const unsigned int*)(rsrc + (long)(nb + r) * 128 + 2 * lane);
      float yx = a[r].x * inv + bf2f(ur & 0xffffu);
      float yy = a[r].y * inv + bf2f(ur >> 16);
      yx = fmaxf(yx * sv.x + tv.x, 0.f);
      yy = fmaxf(yy * sv.y + tv.y, 0.f);
      if (OUTF32) {
        *(float2*)((float*)out + (long)(nb + r) * 128 + 2 * lane) = make_float2(yx, yy);
      } else {
        *(ushort2*)((unsigned short*)out + (long)(nb + r) * 128 + 2 * lane) =
            pk(make_float2(yx, yy));
      }
    }
  }
}

extern "C" void kernel_launch(void* const* d_in, const int* in_sizes, int n_in,
                              void* d_out, int out_size, void* d_ws, size_t ws_size,
                              hipStream_t stream) {
  const float* x   = (const float*)d_in[0];
  const int*   ei  = (const int*)d_in[1];
  const float* W1l = (const float*)d_in[2];
  const float* b1  = (const float*)d_in[3];
  const float* W1r = (const float*)d_in[4];
  const float* g1  = (const float*)d_in[5];
  const float* be1 = (const float*)d_in[6];
  const float* rm1 = (const float*)d_in[7];
  const float* rv1 = (const float*)d_in[8];
  const float* W2l = (const float*)d_in[9];
  const float* b2  = (const float*)d_in[10];
  const float* W2r = (const float*)d_in[11];
  const float* g2  = (const float*)d_in[12];
  const float* be2 = (const float*)d_in[13];
  const float* rm2 = (const float*)d_in[14];
  const float* rv2 = (const float*)d_in[15];

  const int E = in_sizes[1] / 2;
  const int N = in_sizes[0] / 130;
  const int* src = ei;
  const int* dst = ei + E;

  // workspace carve: two (N+1)x128 bf16 ping-pong buffers + packs + CSR (~106 MB)
  unsigned short* bufA = (unsigned short*)d_ws;            // P1l -> P2l (gather targets)
  unsigned short* bufB = bufA + (size_t)(N + 1) * 128;     // P1r -> h1 -> P2r (root/in-place)
  unsigned short* wpka = bufB + (size_t)(N + 1) * 128;     // 5*8192
  unsigned short* wpkb = wpka + 5 * 8192;                  // 4*8192
  float* s1 = (float*)(wpkb + 4 * 8192);
  float* t1 = s1 + 128;
  float* s2 = t1 + 128;
  float* t2 = s2 + 128;
  int* degi   = (int*)(t2 + 128);   // N (reused as cursor)
  int* rowptr = degi + N;           // N+1
  int* bsum   = rowptr + N + 1;     // 256
  int* nbr    = bsum + 256;         // E

  hipLaunchKernelGGL(bn_fold_k, dim3(1), dim3(128), 0, stream,
                     g1, be1, rm1, rv1, b1, g2, be2, rm2, rv2, b2,
                     s1, t1, s2, t2, bufA, N);
  hipLaunchKernelGGL((pack2_k<130, 5>), dim3(160), dim3(256), 0, stream, W1l, W1r, wpka);
  hipLaunchKernelGGL((pack2_k<128, 4>), dim3(128), dim3(256), 0, stream, W2l, W2r, wpkb);

  // CSR build
  hipLaunchKernelGGL(zero_i_k, dim3((N + 255) / 256), dim3(256), 0, stream, degi, N);
  hipLaunchKernelGGL(count_k, dim3((E + 255) / 256), dim3(256), 0, stream, dst, degi, E);
  const int nb = (N + 1023) / 1024;
  hipLaunchKernelGGL(scan1_k, dim3(nb), dim3(256), 0, stream, degi, rowptr, bsum, N);
  hipLaunchKernelGGL(scan2_k, dim3(1), dim3(256), 0, stream, bsum, nb);
  hipLaunchKernelGGL(scan3_k, dim3((N + 256) / 256), dim3(256), 0, stream,
                     rowptr, degi, bsum, N, E);
  hipLaunchKernelGGL(fill_k, dim3((E + 255) / 256), dim3(256), 0, stream,
                     src, dst, degi, nbr, E);

  const int ngb = (N + 63) / 64;
  const int nsb = (N + 15) / 16;

  // layer 1: P1l|P1r = x @ [W1l|W1r]; h1 = relu((mean(P1l[nbr]) + P1r)*s1 + t1') over P1r
  hipLaunchKernelGGL((gemm2_k<5, true>), dim3(ngb), dim3(256), 0, stream,
                     (const void*)x, wpka, bufA, bufB, N);
  hipLaunchKernelGGL((spmm_f_k<false>), dim3(nsb), dim3(256), 0, stream,
                     bufA, bufB, rowptr, nbr, s1, t1, (void*)bufB, N);
  // layer 2: P2l|P2r = h1 @ [W2l|W2r] (in-place over bufA/bufB); out fp32
  hipLaunchKernelGGL((gemm2_k<4, false>), dim3(ngb), dim3(256), 0, stream,
                     (const void*)bufB, wpkb, bufA, bufB, N);
  hipLaunchKernelGGL((spmm_f_k<true>), dim3(nsb), dim3(256), 0, stream,
                     bufA, bufB, rowptr, nbr, s2, t2, d_out, N);
}